// Round 2
// baseline (451.705 us; speedup 1.0000x reference)
//
#include <hip/hip_runtime.h>
#include <hip/hip_bf16.h>
#include <math.h>

typedef unsigned short u16;
typedef __attribute__((ext_vector_type(8))) short bf16x8;
typedef __attribute__((ext_vector_type(8))) unsigned short u16x8;
typedef __attribute__((ext_vector_type(4))) float f32x4;

__device__ __forceinline__ u16 f2b(float f) {
    unsigned x = __float_as_uint(f);
    x += 0x7fffu + ((x >> 16) & 1u);
    return (u16)(x >> 16);
}

__device__ __forceinline__ bf16x8 as_bf(uint4 v) {
    return __builtin_bit_cast(bf16x8, v);
}

// ---------------- transpose + fp32->bf16 convert ----------------
__global__ __launch_bounds__(256) void transpose_cvt(
    const float* __restrict__ in, u16* __restrict__ out,
    int R, int C, long long obs, int ocs)
{
    __shared__ float tile[64][65];
    int c0 = blockIdx.x * 64, r0 = blockIdx.y * 64;
    long long zb = (long long)blockIdx.z;
    const float* ip = in + zb * (long long)R * C;
    u16* op = out + zb * obs;
    int lane = threadIdx.x & 63, w = threadIdx.x >> 6;
#pragma unroll
    for (int i = 0; i < 16; i++) {
        int rr = w + (i << 2);
        tile[rr][lane] = ip[(long long)(r0 + rr) * C + c0 + lane];
    }
    __syncthreads();
#pragma unroll
    for (int i = 0; i < 16; i++) {
        int cc = w + (i << 2);
        op[(long long)(c0 + cc) * ocs + r0 + lane] = f2b(tile[lane][cc]);
    }
}

// ---------------- row layernorm -> bf16 ----------------
__global__ __launch_bounds__(256) void ln_kernel(
    const float* __restrict__ x, const float* __restrict__ w,
    const float* __restrict__ b, u16* __restrict__ out)
{
    int row = blockIdx.x;
    int tid = threadIdx.x;
    float4 v = ((const float4*)(x + (size_t)row * 1024))[tid];
    float s = v.x + v.y + v.z + v.w;
    float s2 = v.x * v.x + v.y * v.y + v.z * v.z + v.w * v.w;
#pragma unroll
    for (int o = 32; o > 0; o >>= 1) {
        s += __shfl_xor(s, o);
        s2 += __shfl_xor(s2, o);
    }
    __shared__ float red[8];
    int wv = tid >> 6;
    if ((tid & 63) == 0) { red[wv] = s; red[4 + wv] = s2; }
    __syncthreads();
    s = red[0] + red[1] + red[2] + red[3];
    s2 = red[4] + red[5] + red[6] + red[7];
    float mean = s * (1.0f / 1024.0f);
    float var = s2 * (1.0f / 1024.0f) - mean * mean;
    float inv = rsqrtf(var + 1e-12f);
    float4 wv4 = ((const float4*)w)[tid];
    float4 bv4 = ((const float4*)b)[tid];
    ushort4 o4;
    o4.x = f2b(wv4.x * (v.x - mean) * inv + bv4.x);
    o4.y = f2b(wv4.y * (v.y - mean) * inv + bv4.y);
    o4.z = f2b(wv4.z * (v.z - mean) * inv + bv4.z);
    o4.w = f2b(wv4.w * (v.w - mean) * inv + bv4.w);
    ((ushort4*)out)[(size_t)row * 256 + tid] = o4;
}

// ---------------- bf16 MFMA GEMM: C[M,N] = A[M,K] * Bt[N,K]^T + bias ----------------
// m97 structure: linear [128][64] LDS + global_load_lds width=16.
template<int EPI>
__global__ __launch_bounds__(256) void gemm_bt(
    const u16* __restrict__ A, const u16* __restrict__ Bt,
    const float* __restrict__ bias, int M, int N, int K,
    float* __restrict__ outf, const float* __restrict__ resid,
    u16* __restrict__ outb,
    u16* __restrict__ qws, float* __restrict__ newk, float* __restrict__ newv,
    u16* __restrict__ Kt, u16* __restrict__ Vt)
{
    __shared__ u16 As[128][64];
    __shared__ u16 Bs[128][64];
    int tid = threadIdx.x;
    int tn0 = blockIdx.x * 128, tm0 = blockIdx.y * 128;
    int wave = tid >> 6, lane = tid & 63;
    int wr = (wave >> 1) * 64, wc = (wave & 1) * 64;
    int lrow = lane & 15, quad = lane >> 4;
    int srow = lane >> 3;            // 0..7
    int scol = (lane & 7) << 3;      // u16 col within 64
    f32x4 acc[4][4] = {};
    for (int k0 = 0; k0 < K; k0 += 64) {
        __syncthreads();
#pragma unroll
        for (int i = 0; i < 4; i++) {
            int r = wave * 32 + i * 8 + srow;
            __builtin_amdgcn_global_load_lds(
                (const __attribute__((address_space(1))) void*)(A + (size_t)(tm0 + r) * K + k0 + scol),
                (__attribute__((address_space(3))) void*)(&As[0][0] + (wave * 4 + i) * 512),
                16, 0, 0);
            __builtin_amdgcn_global_load_lds(
                (const __attribute__((address_space(1))) void*)(Bt + (size_t)(tn0 + r) * K + k0 + scol),
                (__attribute__((address_space(3))) void*)(&Bs[0][0] + (wave * 4 + i) * 512),
                16, 0, 0);
        }
        __syncthreads();
#pragma unroll
        for (int ks = 0; ks < 2; ks++) {
            bf16x8 af[4], bfg[4];
#pragma unroll
            for (int mi = 0; mi < 4; mi++)
                af[mi] = *(const bf16x8*)(&As[wr + mi * 16 + lrow][ks * 32 + quad * 8]);
#pragma unroll
            for (int ni = 0; ni < 4; ni++)
                bfg[ni] = *(const bf16x8*)(&Bs[wc + ni * 16 + lrow][ks * 32 + quad * 8]);
#pragma unroll
            for (int mi = 0; mi < 4; mi++)
#pragma unroll
                for (int ni = 0; ni < 4; ni++)
                    acc[mi][ni] = __builtin_amdgcn_mfma_f32_16x16x32_bf16(
                        af[mi], bfg[ni], acc[mi][ni], 0, 0, 0);
        }
    }
#pragma unroll
    for (int mi = 0; mi < 4; mi++) {
#pragma unroll
        for (int ni = 0; ni < 4; ni++) {
#pragma unroll
            for (int r = 0; r < 4; r++) {
                int m = tm0 + wr + mi * 16 + quad * 4 + r;
                int n = tn0 + wc + ni * 16 + lrow;
                float val = acc[mi][ni][r] + bias[n];
                if (EPI == 0) {
                    int b = m >> 10, s = m & 1023;
                    int d = n & 63;
                    if (n < 1024) {
                        int h = n >> 6;
                        qws[(((size_t)b * 16 + h) * 1024 + s) * 64 + d] = f2b(val);
                    } else if (n < 2048) {
                        int h = (n - 1024) >> 6;
                        newk[(((size_t)b * 16 + h) * 64 + d) * 1024 + s] = val;
                        Kt[(((size_t)b * 16 + h) * 2048 + 1024 + s) * 64 + d] = f2b(val);
                    } else {
                        int h = (n - 2048) >> 6;
                        newv[(((size_t)b * 16 + h) * 1024 + s) * 64 + d] = val;
                        Vt[(((size_t)b * 16 + h) * 64 + d) * 2048 + 1024 + s] = f2b(val);
                    }
                } else if (EPI == 1) {
                    size_t idx = (size_t)m * N + n;
                    outf[idx] = val + resid[idx];
                } else {
                    float t = val + 0.044715f * val * val * val;
                    float gl = 0.5f * val * (1.0f + tanhf(0.7978845608028654f * t));
                    outb[(size_t)m * N + n] = f2b(gl);
                }
            }
        }
    }
}

// ---------------- flash attention: barrier-free, K/V direct from L2 ----------------
// q:  [B,H,S,DH]  bf16  (row s, 64 d)
// Kt: [B,H,T,DH]  bf16  (row t, 64 d)
// Vt: [B,H,DH,T]  bf16  (row d, T t)
// Swapped QK^T: mfma(A=K, B=Q) -> S^T; each lane owns one q-row's scores ->
// in-lane softmax (2 shuffles total). P staged per-wave in LDS (b64 packed),
// PV reads it back as the A-operand. No __syncthreads anywhere in the loop.
__global__ __launch_bounds__(256) void attn_kernel(
    const u16* __restrict__ q, const u16* __restrict__ Kt,
    const u16* __restrict__ Vt, u16* __restrict__ aout)
{
    const int T = 2048;
    __shared__ u16 Ps[4][2][16][72];   // [wave][parity][q-row][t] (+pad)
    int tid = threadIdx.x;
    int bh = blockIdx.y;
    int s0 = blockIdx.x * 64;
    int wave = tid >> 6, lane = tid & 63;
    int lrow = lane & 15, quad = lane >> 4;
    int sw = s0 + wave * 16;
    const u16* qb = q + (((size_t)bh * 1024) + sw + lrow) * 64;
    bf16x8 qf0 = *(const bf16x8*)(qb + quad * 8);
    bf16x8 qf1 = *(const bf16x8*)(qb + 32 + quad * 8);
    const u16* kp = Kt + (size_t)bh * T * 64 + (size_t)lrow * 64 + quad * 8;
    const u16* vp = Vt + (size_t)bh * 64 * T + (size_t)lrow * T + quad * 8;

    // prologue: prefetch K tile 0 fragments
    uint4 kreg[8];
#pragma unroll
    for (int tj = 0; tj < 4; tj++)
#pragma unroll
        for (int ks = 0; ks < 2; ks++)
            kreg[tj * 2 + ks] = *(const uint4*)(kp + (size_t)(tj * 16) * 64 + ks * 32);

    f32x4 Oacc[4] = {};
    float mrun = -1e30f, lrun = 0.0f;

    for (int t0 = 0, pp = 0; t0 < T; t0 += 64, pp ^= 1) {
        // ---- QK^T (swapped): sc[tj][r] = S[q=lrow][t0 + tj*16 + quad*4 + r]
        f32x4 sc[4];
#pragma unroll
        for (int tj = 0; tj < 4; tj++) {
            f32x4 z = {};
            z = __builtin_amdgcn_mfma_f32_16x16x32_bf16(as_bf(kreg[tj * 2 + 0]), qf0, z, 0, 0, 0);
            z = __builtin_amdgcn_mfma_f32_16x16x32_bf16(as_bf(kreg[tj * 2 + 1]), qf1, z, 0, 0, 0);
            sc[tj] = z;
        }
        // ---- issue V loads for this tile (latency hides under softmax)
        uint4 vreg[8];
#pragma unroll
        for (int dj = 0; dj < 4; dj++)
#pragma unroll
            for (int ks = 0; ks < 2; ks++)
                vreg[dj * 2 + ks] = *(const uint4*)(vp + (size_t)(dj * 16) * T + t0 + ks * 32);
        // ---- prefetch next K tile
        if (t0 + 64 < T) {
#pragma unroll
            for (int tj = 0; tj < 4; tj++)
#pragma unroll
                for (int ks = 0; ks < 2; ks++)
                    kreg[tj * 2 + ks] = *(const uint4*)(kp + (size_t)(t0 + 64 + tj * 16) * 64 + ks * 32);
        }
        // ---- in-lane softmax for q = lrow
        float mx = sc[0][0];
#pragma unroll
        for (int tj = 0; tj < 4; tj++)
#pragma unroll
            for (int r = 0; r < 4; r++) mx = fmaxf(mx, sc[tj][r]);
        mx = fmaxf(mx, __shfl_xor(mx, 16));
        mx = fmaxf(mx, __shfl_xor(mx, 32));
        if (__any(mx > mrun + 8.0f)) {           // defer-max rescale (rare)
            bool need = mx > mrun + 8.0f;
            float scl = need ? __expf(mrun - mx) : 1.0f;
            lrun *= scl;
            if (need) mrun = mx;
#pragma unroll
            for (int r = 0; r < 4; r++) {
                float sr = __shfl(scl, quad * 4 + r);
#pragma unroll
                for (int dj = 0; dj < 4; dj++) Oacc[dj][r] *= sr;
            }
        }
        float ps = 0.0f;
#pragma unroll
        for (int tj = 0; tj < 4; tj++) {
            float p0 = __expf(sc[tj][0] - mrun);
            float p1 = __expf(sc[tj][1] - mrun);
            float p2 = __expf(sc[tj][2] - mrun);
            float p3 = __expf(sc[tj][3] - mrun);
            ps += (p0 + p1) + (p2 + p3);
            ushort4 hh;
            hh.x = f2b(p0); hh.y = f2b(p1); hh.z = f2b(p2); hh.w = f2b(p3);
            *(ushort4*)(&Ps[wave][pp][lrow][tj * 16 + quad * 4]) = hh;
        }
        ps += __shfl_xor(ps, 16);
        ps += __shfl_xor(ps, 32);
        lrun += ps;
        // wave-private Ps: cross-lane visibility needs only the LDS queue drained
        asm volatile("s_waitcnt lgkmcnt(0)" ::: "memory");
        // ---- PV: Oacc[q=quad*4+r][d=dj*16+lrow]
#pragma unroll
        for (int ks = 0; ks < 2; ks++) {
            bf16x8 pf = *(const bf16x8*)(&Ps[wave][pp][lrow][ks * 32 + quad * 8]);
#pragma unroll
            for (int dj = 0; dj < 4; dj++)
                Oacc[dj] = __builtin_amdgcn_mfma_f32_16x16x32_bf16(pf, as_bf(vreg[dj * 2 + ks]), Oacc[dj], 0, 0, 0);
        }
    }
    // ---- epilogue
    int b = bh >> 4, h = bh & 15;
#pragma unroll
    for (int r = 0; r < 4; r++) {
        float linv = 1.0f / __shfl(lrun, quad * 4 + r);
        int s = sw + quad * 4 + r;
#pragma unroll
        for (int dj = 0; dj < 4; dj++) {
            int d = dj * 16 + lrow;
            aout[((size_t)b * 1024 + s) * 1024 + h * 64 + d] = f2b(Oacc[dj][r] * linv);
        }
    }
}

extern "C" void kernel_launch(void* const* d_in, const int* in_sizes, int n_in,
                              void* d_out, int out_size, void* d_ws, size_t ws_size,
                              hipStream_t stream)
{
    const float* x      = (const float*)d_in[0];
    const float* kin    = (const float*)d_in[1];
    const float* vin    = (const float*)d_in[2];
    const float* ln1w   = (const float*)d_in[3];
    const float* ln1b   = (const float*)d_in[4];
    const float* ln2w   = (const float*)d_in[5];
    const float* ln2b   = (const float*)d_in[6];
    const float* w_attn = (const float*)d_in[7];
    const float* b_attn = (const float*)d_in[8];
    const float* w_proj = (const float*)d_in[9];
    const float* b_proj = (const float*)d_in[10];
    const float* w_fc   = (const float*)d_in[11];
    const float* b_fc   = (const float*)d_in[12];
    const float* w_fc2  = (const float*)d_in[13];
    const float* b_fc2  = (const float*)d_in[14];

    float* xout = (float*)d_out;
    float* newk = xout + 2097152;
    float* newv = newk + 2097152;

    char* w = (char*)d_ws;
    u16* wT_attn = (u16*)w;  w += 6291456;   // [3072,1024]
    u16* wT_proj = (u16*)w;  w += 2097152;   // [1024,1024]
    u16* wT_fc   = (u16*)w;  w += 8388608;   // [4096,1024]
    u16* wT_fc2  = (u16*)w;  w += 8388608;   // [1024,4096]
    u16* h1a     = (u16*)w;  w += 4194304;   // ln1 out, later attn out [B,S,D]
    u16* qh2     = (u16*)w;  w += 4194304;   // q [B,H,S,DH], later ln2 out
    u16* Kt      = (u16*)w;  w += 8388608;   // [B,H,2048,64]
    u16* Vt      = (u16*)w;  w += 8388608;   // [B,H,64,2048]
    u16* g       = (u16*)w;                  // [2048,4096] 16 MB

    dim3 blk(256);
    // weights -> bf16 transposed [N,K]
    transpose_cvt<<<dim3(48, 16, 1), blk, 0, stream>>>(w_attn, wT_attn, 1024, 3072, 0, 1024);
    transpose_cvt<<<dim3(16, 16, 1), blk, 0, stream>>>(w_proj, wT_proj, 1024, 1024, 0, 1024);
    transpose_cvt<<<dim3(64, 16, 1), blk, 0, stream>>>(w_fc,   wT_fc,   1024, 4096, 0, 1024);
    transpose_cvt<<<dim3(16, 64, 1), blk, 0, stream>>>(w_fc2,  wT_fc2,  4096, 1024, 0, 4096);
    // past K [b,h,d,t] -> Kt[b,h,t,d] (t<1024); past V [b,h,t,d] -> Vt[b,h,d,t]
    transpose_cvt<<<dim3(16, 1, 32), blk, 0, stream>>>(kin, Kt, 64, 1024, 131072, 64);
    transpose_cvt<<<dim3(1, 16, 32), blk, 0, stream>>>(vin, Vt, 1024, 64, 131072, 2048);

    ln_kernel<<<2048, blk, 0, stream>>>(x, ln1w, ln1b, h1a);

    gemm_bt<0><<<dim3(24, 16), blk, 0, stream>>>(h1a, wT_attn, b_attn, 2048, 3072, 1024,
        nullptr, nullptr, nullptr, qh2, newk, newv, Kt, Vt);

    attn_kernel<<<dim3(16, 32), blk, 0, stream>>>(qh2, Kt, Vt, h1a);

    gemm_bt<1><<<dim3(8, 16), blk, 0, stream>>>(h1a, wT_proj, b_proj, 2048, 1024, 1024,
        xout, x, nullptr, nullptr, nullptr, nullptr, nullptr, nullptr);

    ln_kernel<<<2048, blk, 0, stream>>>(xout, ln2w, ln2b, qh2);

    gemm_bt<2><<<dim3(32, 16), blk, 0, stream>>>(qh2, wT_fc, b_fc, 2048, 4096, 1024,
        nullptr, nullptr, g, nullptr, nullptr, nullptr, nullptr, nullptr);

    gemm_bt<1><<<dim3(8, 16), blk, 0, stream>>>(g, wT_fc2, b_fc2, 2048, 1024, 4096,
        xout, xout, nullptr, nullptr, nullptr, nullptr, nullptr, nullptr);
}

// Round 3
// 419.096 us; speedup vs baseline: 1.0778x; 1.0778x over previous
//
#include <hip/hip_runtime.h>
#include <hip/hip_bf16.h>
#include <math.h>

typedef unsigned short u16;
typedef __attribute__((ext_vector_type(8))) short bf16x8;
typedef __attribute__((ext_vector_type(8))) unsigned short u16x8;
typedef __attribute__((ext_vector_type(4))) float f32x4;

__device__ __forceinline__ u16 f2b(float f) {
    unsigned x = __float_as_uint(f);
    x += 0x7fffu + ((x >> 16) & 1u);
    return (u16)(x >> 16);
}

// ---------------- transpose + fp32->bf16 convert ----------------
__global__ __launch_bounds__(256) void transpose_cvt(
    const float* __restrict__ in, u16* __restrict__ out,
    int R, int C, long long obs, int ocs)
{
    __shared__ float tile[64][65];
    int c0 = blockIdx.x * 64, r0 = blockIdx.y * 64;
    long long zb = (long long)blockIdx.z;
    const float* ip = in + zb * (long long)R * C;
    u16* op = out + zb * obs;
    int lane = threadIdx.x & 63, w = threadIdx.x >> 6;
#pragma unroll
    for (int i = 0; i < 16; i++) {
        int rr = w + (i << 2);
        tile[rr][lane] = ip[(long long)(r0 + rr) * C + c0 + lane];
    }
    __syncthreads();
#pragma unroll
    for (int i = 0; i < 16; i++) {
        int cc = w + (i << 2);
        op[(long long)(c0 + cc) * ocs + r0 + lane] = f2b(tile[lane][cc]);
    }
}

// ---------------- row layernorm -> bf16 ----------------
__global__ __launch_bounds__(256) void ln_kernel(
    const float* __restrict__ x, const float* __restrict__ w,
    const float* __restrict__ b, u16* __restrict__ out)
{
    int row = blockIdx.x;
    int tid = threadIdx.x;
    float4 v = ((const float4*)(x + (size_t)row * 1024))[tid];
    float s = v.x + v.y + v.z + v.w;
    float s2 = v.x * v.x + v.y * v.y + v.z * v.z + v.w * v.w;
#pragma unroll
    for (int o = 32; o > 0; o >>= 1) {
        s += __shfl_xor(s, o);
        s2 += __shfl_xor(s2, o);
    }
    __shared__ float red[8];
    int wv = tid >> 6;
    if ((tid & 63) == 0) { red[wv] = s; red[4 + wv] = s2; }
    __syncthreads();
    s = red[0] + red[1] + red[2] + red[3];
    s2 = red[4] + red[5] + red[6] + red[7];
    float mean = s * (1.0f / 1024.0f);
    float var = s2 * (1.0f / 1024.0f) - mean * mean;
    float inv = rsqrtf(var + 1e-12f);
    float4 wv4 = ((const float4*)w)[tid];
    float4 bv4 = ((const float4*)b)[tid];
    ushort4 o4;
    o4.x = f2b(wv4.x * (v.x - mean) * inv + bv4.x);
    o4.y = f2b(wv4.y * (v.y - mean) * inv + bv4.y);
    o4.z = f2b(wv4.z * (v.z - mean) * inv + bv4.z);
    o4.w = f2b(wv4.w * (v.w - mean) * inv + bv4.w);
    ((ushort4*)out)[(size_t)row * 256 + tid] = o4;
}

// ---------------- bf16 MFMA GEMM: C[M,N] = A[M,K] * Bt[N,K]^T + bias ----------------
// m97 structure: linear [128][64] LDS + global_load_lds width=16.
template<int EPI>
__global__ __launch_bounds__(256) void gemm_bt(
    const u16* __restrict__ A, const u16* __restrict__ Bt,
    const float* __restrict__ bias, int M, int N, int K,
    float* __restrict__ outf, const float* __restrict__ resid,
    u16* __restrict__ outb,
    u16* __restrict__ qws, float* __restrict__ newk, float* __restrict__ newv,
    u16* __restrict__ Kt, u16* __restrict__ Vt)
{
    __shared__ u16 As[128][64];
    __shared__ u16 Bs[128][64];
    int tid = threadIdx.x;
    int tn0 = blockIdx.x * 128, tm0 = blockIdx.y * 128;
    int wave = tid >> 6, lane = tid & 63;
    int wr = (wave >> 1) * 64, wc = (wave & 1) * 64;
    int lrow = lane & 15, quad = lane >> 4;
    int srow = lane >> 3;            // 0..7
    int scol = (lane & 7) << 3;      // u16 col within 64
    f32x4 acc[4][4] = {};
    for (int k0 = 0; k0 < K; k0 += 64) {
        __syncthreads();
#pragma unroll
        for (int i = 0; i < 4; i++) {
            int r = wave * 32 + i * 8 + srow;
            __builtin_amdgcn_global_load_lds(
                (const __attribute__((address_space(1))) void*)(A + (size_t)(tm0 + r) * K + k0 + scol),
                (__attribute__((address_space(3))) void*)(&As[0][0] + (wave * 4 + i) * 512),
                16, 0, 0);
            __builtin_amdgcn_global_load_lds(
                (const __attribute__((address_space(1))) void*)(Bt + (size_t)(tn0 + r) * K + k0 + scol),
                (__attribute__((address_space(3))) void*)(&Bs[0][0] + (wave * 4 + i) * 512),
                16, 0, 0);
        }
        __syncthreads();
#pragma unroll
        for (int ks = 0; ks < 2; ks++) {
            bf16x8 af[4], bfg[4];
#pragma unroll
            for (int mi = 0; mi < 4; mi++)
                af[mi] = *(const bf16x8*)(&As[wr + mi * 16 + lrow][ks * 32 + quad * 8]);
#pragma unroll
            for (int ni = 0; ni < 4; ni++)
                bfg[ni] = *(const bf16x8*)(&Bs[wc + ni * 16 + lrow][ks * 32 + quad * 8]);
#pragma unroll
            for (int mi = 0; mi < 4; mi++)
#pragma unroll
                for (int ni = 0; ni < 4; ni++)
                    acc[mi][ni] = __builtin_amdgcn_mfma_f32_16x16x32_bf16(
                        af[mi], bfg[ni], acc[mi][ni], 0, 0, 0);
        }
    }
#pragma unroll
    for (int mi = 0; mi < 4; mi++) {
#pragma unroll
        for (int ni = 0; ni < 4; ni++) {
#pragma unroll
            for (int r = 0; r < 4; r++) {
                int m = tm0 + wr + mi * 16 + quad * 4 + r;
                int n = tn0 + wc + ni * 16 + lrow;
                float val = acc[mi][ni][r] + bias[n];
                if (EPI == 0) {
                    int b = m >> 10, s = m & 1023;
                    int d = n & 63;
                    if (n < 1024) {
                        int h = n >> 6;
                        qws[(((size_t)b * 16 + h) * 1024 + s) * 64 + d] = f2b(val);
                    } else if (n < 2048) {
                        int h = (n - 1024) >> 6;
                        newk[(((size_t)b * 16 + h) * 64 + d) * 1024 + s] = val;
                        Kt[(((size_t)b * 16 + h) * 2048 + 1024 + s) * 64 + d] = f2b(val);
                    } else {
                        int h = (n - 2048) >> 6;
                        newv[(((size_t)b * 16 + h) * 1024 + s) * 64 + d] = val;
                        Vt[(((size_t)b * 16 + h) * 64 + d) * 2048 + 1024 + s] = f2b(val);
                    }
                } else if (EPI == 1) {
                    size_t idx = (size_t)m * N + n;
                    outf[idx] = val + resid[idx];
                } else {
                    float t = val + 0.044715f * val * val * val;
                    float gl = 0.5f * val * (1.0f + tanhf(0.7978845608028654f * t));
                    outb[(size_t)m * N + n] = f2b(gl);
                }
            }
        }
    }
}

// ---------------- flash attention ----------------
// q:  [B,H,S,DH] bf16;  Kt: [B,H,T,DH] bf16;  Vt: [B,H,DH,T] bf16.
// Head-clustered XCD swizzle: xcd = wgid&7 owns 4 heads (2 MB KV -> L2-resident).
// Double-buffered cooperative K/V staging: ONE barrier per tile.
// Swapped QK^T (mfma(K,Q) -> S^T): in-lane softmax, 2 shuffles per reduce.
__global__ __launch_bounds__(256) void attn_kernel(
    const u16* __restrict__ q, const u16* __restrict__ Kt,
    const u16* __restrict__ Vt, u16* __restrict__ aout)
{
    const int T = 2048;
    __shared__ u16 Ks[2][64][72];
    __shared__ u16 Vs[2][64][72];
    __shared__ u16 Ps[4][16][72];
    int tid = threadIdx.x;
    // head-clustered XCD swizzle (perf-only; correctness doesn't depend on mapping)
    int wg = blockIdx.y * 16 + blockIdx.x;      // 0..511
    int xcd = wg & 7, local = wg >> 3;          // dispatch round-robins wgid%8 -> XCD
    int bh = xcd * 4 + (local >> 4);            // 4 heads per XCD
    int s0 = (local & 15) * 64;
    int wave = tid >> 6, lane = tid & 63;
    int lrow = lane & 15, quad = lane >> 4;
    int sw = s0 + wave * 16;
    const u16* qb = q + (((size_t)bh * 1024) + sw + lrow) * 64;
    bf16x8 qf0 = *(const bf16x8*)(qb + quad * 8);
    bf16x8 qf1 = *(const bf16x8*)(qb + 32 + quad * 8);
    const u16* Kb = Kt + (size_t)bh * T * 64;
    const u16* Vb = Vt + (size_t)bh * 64 * T;
    int srow = tid >> 3, scol = (tid & 7) << 3;

    // prologue: tile0 -> LDS[0]; tile1 -> regs
    uint4 kr[2], vr[2];
#pragma unroll
    for (int i = 0; i < 2; i++) {
        kr[i] = *(const uint4*)(Kb + (size_t)(srow + i * 32) * 64 + scol);
        vr[i] = *(const uint4*)(Vb + (size_t)(srow + i * 32) * T + scol);
    }
#pragma unroll
    for (int i = 0; i < 2; i++) {
        *(uint4*)(&Ks[0][srow + i * 32][scol]) = kr[i];
        *(uint4*)(&Vs[0][srow + i * 32][scol]) = vr[i];
    }
#pragma unroll
    for (int i = 0; i < 2; i++) {
        kr[i] = *(const uint4*)(Kb + (size_t)(64 + srow + i * 32) * 64 + scol);
        vr[i] = *(const uint4*)(Vb + (size_t)(srow + i * 32) * T + 64 + scol);
    }
    __syncthreads();

    f32x4 Oacc[4] = {};
    float mrun = -1e30f, lrun = 0.0f;

    for (int t0 = 0; t0 < T; t0 += 64) {
        int cur = (t0 >> 6) & 1, nxt = cur ^ 1;
        // stage tile t0+64 (regs -> LDS[nxt]); safe: barrier at end of prev iter
        if (t0 + 64 < T) {
#pragma unroll
            for (int i = 0; i < 2; i++) {
                *(uint4*)(&Ks[nxt][srow + i * 32][scol]) = kr[i];
                *(uint4*)(&Vs[nxt][srow + i * 32][scol]) = vr[i];
            }
        }
        // prefetch tile t0+128 into regs; full tile of compute to hide latency
        if (t0 + 128 < T) {
#pragma unroll
            for (int i = 0; i < 2; i++) {
                kr[i] = *(const uint4*)(Kb + (size_t)(t0 + 128 + srow + i * 32) * 64 + scol);
                vr[i] = *(const uint4*)(Vb + (size_t)(srow + i * 32) * T + t0 + 128 + scol);
            }
        }
        // ---- QK^T (swapped): sc[tj][r] = S[q=lrow][t0 + tj*16 + quad*4 + r]
        f32x4 sc[4];
        __builtin_amdgcn_s_setprio(1);
#pragma unroll
        for (int tj = 0; tj < 4; tj++) {
            bf16x8 kf0 = *(const bf16x8*)(&Ks[cur][tj * 16 + lrow][quad * 8]);
            bf16x8 kf1 = *(const bf16x8*)(&Ks[cur][tj * 16 + lrow][32 + quad * 8]);
            f32x4 z = {};
            z = __builtin_amdgcn_mfma_f32_16x16x32_bf16(kf0, qf0, z, 0, 0, 0);
            z = __builtin_amdgcn_mfma_f32_16x16x32_bf16(kf1, qf1, z, 0, 0, 0);
            sc[tj] = z;
        }
        __builtin_amdgcn_s_setprio(0);
        // ---- in-lane softmax for q = lrow (16 scores in-lane + 2 shuffles)
        float mx = sc[0][0];
#pragma unroll
        for (int tj = 0; tj < 4; tj++)
#pragma unroll
            for (int r = 0; r < 4; r++) mx = fmaxf(mx, sc[tj][r]);
        mx = fmaxf(mx, __shfl_xor(mx, 16));
        mx = fmaxf(mx, __shfl_xor(mx, 32));
        if (__any(mx > mrun + 8.0f)) {           // defer-max rescale (rare)
            bool need = mx > mrun + 8.0f;
            float scl = need ? __expf(mrun - mx) : 1.0f;
            lrun *= scl;
            if (need) mrun = mx;
#pragma unroll
            for (int r = 0; r < 4; r++) {
                float sr = __shfl(scl, quad * 4 + r);
#pragma unroll
                for (int dj = 0; dj < 4; dj++) Oacc[dj][r] *= sr;
            }
        }
        float ps = 0.0f;
#pragma unroll
        for (int tj = 0; tj < 4; tj++) {
            float p0 = __expf(sc[tj][0] - mrun);
            float p1 = __expf(sc[tj][1] - mrun);
            float p2 = __expf(sc[tj][2] - mrun);
            float p3 = __expf(sc[tj][3] - mrun);
            ps += (p0 + p1) + (p2 + p3);
            ushort4 hh;
            hh.x = f2b(p0); hh.y = f2b(p1); hh.z = f2b(p2); hh.w = f2b(p3);
            *(ushort4*)(&Ps[wave][lrow][tj * 16 + quad * 4]) = hh;
        }
        ps += __shfl_xor(ps, 16);
        ps += __shfl_xor(ps, 32);
        lrun += ps;
        // Ps is wave-private: drain LDS queue; fence scheduler (guide rule #18)
        asm volatile("s_waitcnt lgkmcnt(0)" ::: "memory");
        __builtin_amdgcn_sched_barrier(0);
        // ---- PV: Oacc[dj][r] = O[q=quad*4+r][d=dj*16+lrow]
        __builtin_amdgcn_s_setprio(1);
#pragma unroll
        for (int ks = 0; ks < 2; ks++) {
            bf16x8 pf = *(const bf16x8*)(&Ps[wave][lrow][ks * 32 + quad * 8]);
#pragma unroll
            for (int dj = 0; dj < 4; dj++) {
                bf16x8 vf = *(const bf16x8*)(&Vs[cur][dj * 16 + lrow][ks * 32 + quad * 8]);
                Oacc[dj] = __builtin_amdgcn_mfma_f32_16x16x32_bf16(pf, vf, Oacc[dj], 0, 0, 0);
            }
        }
        __builtin_amdgcn_s_setprio(0);
        __syncthreads();   // single barrier per tile: LDS[cur] reads done before overwrite
    }
    // ---- epilogue
    int b = bh >> 4, h = bh & 15;
#pragma unroll
    for (int r = 0; r < 4; r++) {
        float linv = 1.0f / __shfl(lrun, quad * 4 + r);
        int s = sw + quad * 4 + r;
#pragma unroll
        for (int dj = 0; dj < 4; dj++) {
            int d = dj * 16 + lrow;
            aout[((size_t)b * 1024 + s) * 1024 + h * 64 + d] = f2b(Oacc[dj][r] * linv);
        }
    }
}

extern "C" void kernel_launch(void* const* d_in, const int* in_sizes, int n_in,
                              void* d_out, int out_size, void* d_ws, size_t ws_size,
                              hipStream_t stream)
{
    const float* x      = (const float*)d_in[0];
    const float* kin    = (const float*)d_in[1];
    const float* vin    = (const float*)d_in[2];
    const float* ln1w   = (const float*)d_in[3];
    const float* ln1b   = (const float*)d_in[4];
    const float* ln2w   = (const float*)d_in[5];
    const float* ln2b   = (const float*)d_in[6];
    const float* w_attn = (const float*)d_in[7];
    const float* b_attn = (const float*)d_in[8];
    const float* w_proj = (const float*)d_in[9];
    const float* b_proj = (const float*)d_in[10];
    const float* w_fc   = (const float*)d_in[11];
    const float* b_fc   = (const float*)d_in[12];
    const float* w_fc2  = (const float*)d_in[13];
    const float* b_fc2  = (const float*)d_in[14];

    float* xout = (float*)d_out;
    float* newk = xout + 2097152;
    float* newv = newk + 2097152;

    char* w = (char*)d_ws;
    u16* wT_attn = (u16*)w;  w += 6291456;   // [3072,1024]
    u16* wT_proj = (u16*)w;  w += 2097152;   // [1024,1024]
    u16* wT_fc   = (u16*)w;  w += 8388608;   // [4096,1024]
    u16* wT_fc2  = (u16*)w;  w += 8388608;   // [1024,4096]
    u16* h1a     = (u16*)w;  w += 4194304;   // ln1 out, later attn out [B,S,D]
    u16* qh2     = (u16*)w;  w += 4194304;   // q [B,H,S,DH], later ln2 out
    u16* Kt      = (u16*)w;  w += 8388608;   // [B,H,2048,64]
    u16* Vt      = (u16*)w;  w += 8388608;   // [B,H,64,2048]
    u16* g       = (u16*)w;                  // [2048,4096] 16 MB

    dim3 blk(256);
    // weights -> bf16 transposed [N,K]
    transpose_cvt<<<dim3(48, 16, 1), blk, 0, stream>>>(w_attn, wT_attn, 1024, 3072, 0, 1024);
    transpose_cvt<<<dim3(16, 16, 1), blk, 0, stream>>>(w_proj, wT_proj, 1024, 1024, 0, 1024);
    transpose_cvt<<<dim3(64, 16, 1), blk, 0, stream>>>(w_fc,   wT_fc,   1024, 4096, 0, 1024);
    transpose_cvt<<<dim3(16, 64, 1), blk, 0, stream>>>(w_fc2,  wT_fc2,  4096, 1024, 0, 4096);
    // past K [b,h,d,t] -> Kt[b,h,t,d] (t<1024); past V [b,h,t,d] -> Vt[b,h,d,t]
    transpose_cvt<<<dim3(16, 1, 32), blk, 0, stream>>>(kin, Kt, 64, 1024, 131072, 64);
    transpose_cvt<<<dim3(1, 16, 32), blk, 0, stream>>>(vin, Vt, 1024, 64, 131072, 2048);

    ln_kernel<<<2048, blk, 0, stream>>>(x, ln1w, ln1b, h1a);

    gemm_bt<0><<<dim3(24, 16), blk, 0, stream>>>(h1a, wT_attn, b_attn, 2048, 3072, 1024,
        nullptr, nullptr, nullptr, qh2, newk, newv, Kt, Vt);

    attn_kernel<<<dim3(16, 32), blk, 0, stream>>>(qh2, Kt, Vt, h1a);

    gemm_bt<1><<<dim3(8, 16), blk, 0, stream>>>(h1a, wT_proj, b_proj, 2048, 1024, 1024,
        xout, x, nullptr, nullptr, nullptr, nullptr, nullptr, nullptr);

    ln_kernel<<<2048, blk, 0, stream>>>(xout, ln2w, ln2b, qh2);

    gemm_bt<2><<<dim3(32, 16), blk, 0, stream>>>(qh2, wT_fc, b_fc, 2048, 4096, 1024,
        nullptr, nullptr, g, nullptr, nullptr, nullptr, nullptr, nullptr);

    gemm_bt<1><<<dim3(8, 16), blk, 0, stream>>>(g, wT_fc2, b_fc2, 2048, 1024, 4096,
        xout, xout, nullptr, nullptr, nullptr, nullptr, nullptr, nullptr);
}

// Round 4
// 398.588 us; speedup vs baseline: 1.1333x; 1.0515x over previous
//
#include <hip/hip_runtime.h>
#include <hip/hip_bf16.h>
#include <math.h>

typedef unsigned short u16;
typedef __attribute__((ext_vector_type(8))) short bf16x8;
typedef __attribute__((ext_vector_type(8))) unsigned short u16x8;
typedef __attribute__((ext_vector_type(4))) float f32x4;

__device__ __forceinline__ u16 f2b(float f) {
    unsigned x = __float_as_uint(f);
    x += 0x7fffu + ((x >> 16) & 1u);
    return (u16)(x >> 16);
}

// ---------------- transpose + fp32->bf16 convert ----------------
__global__ __launch_bounds__(256) void transpose_cvt(
    const float* __restrict__ in, u16* __restrict__ out,
    int R, int C, long long obs, int ocs)
{
    __shared__ float tile[64][65];
    int c0 = blockIdx.x * 64, r0 = blockIdx.y * 64;
    long long zb = (long long)blockIdx.z;
    const float* ip = in + zb * (long long)R * C;
    u16* op = out + zb * obs;
    int lane = threadIdx.x & 63, w = threadIdx.x >> 6;
#pragma unroll
    for (int i = 0; i < 16; i++) {
        int rr = w + (i << 2);
        tile[rr][lane] = ip[(long long)(r0 + rr) * C + c0 + lane];
    }
    __syncthreads();
#pragma unroll
    for (int i = 0; i < 16; i++) {
        int cc = w + (i << 2);
        op[(long long)(c0 + cc) * ocs + r0 + lane] = f2b(tile[lane][cc]);
    }
}

// ---------------- row layernorm -> bf16 ----------------
__global__ __launch_bounds__(256) void ln_kernel(
    const float* __restrict__ x, const float* __restrict__ w,
    const float* __restrict__ b, u16* __restrict__ out)
{
    int row = blockIdx.x;
    int tid = threadIdx.x;
    float4 v = ((const float4*)(x + (size_t)row * 1024))[tid];
    float s = v.x + v.y + v.z + v.w;
    float s2 = v.x * v.x + v.y * v.y + v.z * v.z + v.w * v.w;
#pragma unroll
    for (int o = 32; o > 0; o >>= 1) {
        s += __shfl_xor(s, o);
        s2 += __shfl_xor(s2, o);
    }
    __shared__ float red[8];
    int wv = tid >> 6;
    if ((tid & 63) == 0) { red[wv] = s; red[4 + wv] = s2; }
    __syncthreads();
    s = red[0] + red[1] + red[2] + red[3];
    s2 = red[4] + red[5] + red[6] + red[7];
    float mean = s * (1.0f / 1024.0f);
    float var = s2 * (1.0f / 1024.0f) - mean * mean;
    float inv = rsqrtf(var + 1e-12f);
    float4 wv4 = ((const float4*)w)[tid];
    float4 bv4 = ((const float4*)b)[tid];
    ushort4 o4;
    o4.x = f2b(wv4.x * (v.x - mean) * inv + bv4.x);
    o4.y = f2b(wv4.y * (v.y - mean) * inv + bv4.y);
    o4.z = f2b(wv4.z * (v.z - mean) * inv + bv4.z);
    o4.w = f2b(wv4.w * (v.w - mean) * inv + bv4.w);
    ((ushort4*)out)[(size_t)row * 256 + tid] = o4;
}

// ---------------- bf16 MFMA GEMM: C[M,N] = A[M,K] * Bt[N,K]^T + bias ----------------
// 2-phase pipeline: dbuf LDS, prefetch-before-compute, ONE barrier per K-step.
// Bijective XCD swizzle on flat block id (all grids divisible by 8).
// EPI 0: qkv scatter; 1: f32 out + resid; 2: gelu->bf16; 3: split-K atomicAdd into outf.
template<int EPI>
__global__ __launch_bounds__(256) void gemm_bt(
    const u16* __restrict__ A, const u16* __restrict__ Bt,
    const float* __restrict__ bias, int M, int N, int K, int Kc,
    float* __restrict__ outf, const float* __restrict__ resid,
    u16* __restrict__ outb,
    u16* __restrict__ qws, float* __restrict__ newk, float* __restrict__ newv,
    u16* __restrict__ Kt, u16* __restrict__ Vt)
{
    __shared__ u16 As[2][128][64];
    __shared__ u16 Bs[2][128][64];
    int tid = threadIdx.x;
    // T1 bijective XCD swizzle over the flat grid (nwg % 8 == 0 for all our launches)
    int gx = gridDim.x, gy = gridDim.y;
    int nwg = gx * gy * gridDim.z;
    int f = blockIdx.x + gx * (blockIdx.y + gy * blockIdx.z);
    int swz = (f & 7) * (nwg >> 3) + (f >> 3);
    int bx = swz % gx;
    int rest = swz / gx;
    int by = rest % gy;
    int chunk = rest / gy;
    int tn0 = bx * 128, tm0 = by * 128;
    int kbeg = chunk * Kc, kend = kbeg + Kc;

    int wave = tid >> 6, lane = tid & 63;
    int wr = (wave >> 1) * 64, wc = (wave & 1) * 64;
    int lrow = lane & 15, quad = lane >> 4;
    int srow = lane >> 3;            // 0..7
    int scol = (lane & 7) << 3;      // u16 col within 64

    // stage one 128x64 K-tile of A and B into buffer b
#define STAGE(k0, b)                                                                     \
    _Pragma("unroll")                                                                    \
    for (int i = 0; i < 4; i++) {                                                        \
        int r = wave * 32 + i * 8 + srow;                                                \
        __builtin_amdgcn_global_load_lds(                                                \
            (const __attribute__((address_space(1))) void*)(A + (size_t)(tm0 + r) * K + (k0) + scol), \
            (__attribute__((address_space(3))) void*)(&As[b][0][0] + (wave * 4 + i) * 512), \
            16, 0, 0);                                                                   \
        __builtin_amdgcn_global_load_lds(                                                \
            (const __attribute__((address_space(1))) void*)(Bt + (size_t)(tn0 + r) * K + (k0) + scol), \
            (__attribute__((address_space(3))) void*)(&Bs[b][0][0] + (wave * 4 + i) * 512), \
            16, 0, 0);                                                                   \
    }

    f32x4 acc[4][4] = {};
    STAGE(kbeg, 0);
    __syncthreads();                 // compiler drains vmcnt before barrier
    int buf = 0;
    for (int k0 = kbeg; k0 < kend; k0 += 64) {
        if (k0 + 64 < kend) { STAGE(k0 + 64, buf ^ 1); }   // in flight during MFMA
#pragma unroll
        for (int ks = 0; ks < 2; ks++) {
            bf16x8 af[4], bfg[4];
#pragma unroll
            for (int mi = 0; mi < 4; mi++)
                af[mi] = *(const bf16x8*)(&As[buf][wr + mi * 16 + lrow][ks * 32 + quad * 8]);
#pragma unroll
            for (int ni = 0; ni < 4; ni++)
                bfg[ni] = *(const bf16x8*)(&Bs[buf][wc + ni * 16 + lrow][ks * 32 + quad * 8]);
#pragma unroll
            for (int mi = 0; mi < 4; mi++)
#pragma unroll
                for (int ni = 0; ni < 4; ni++)
                    acc[mi][ni] = __builtin_amdgcn_mfma_f32_16x16x32_bf16(
                        af[mi], bfg[ni], acc[mi][ni], 0, 0, 0);
        }
        __syncthreads();             // next buf staged (vmcnt drained) + cur reads done
        buf ^= 1;
    }
#undef STAGE

#pragma unroll
    for (int mi = 0; mi < 4; mi++) {
#pragma unroll
        for (int ni = 0; ni < 4; ni++) {
#pragma unroll
            for (int r = 0; r < 4; r++) {
                int m = tm0 + wr + mi * 16 + quad * 4 + r;
                int n = tn0 + wc + ni * 16 + lrow;
                float val = acc[mi][ni][r] +
                            ((EPI != 3 || chunk == 0) ? bias[n] : 0.0f);
                if (EPI == 0) {
                    int b = m >> 10, s = m & 1023;
                    int d = n & 63;
                    if (n < 1024) {
                        int h = n >> 6;
                        qws[(((size_t)b * 16 + h) * 1024 + s) * 64 + d] = f2b(val);
                    } else if (n < 2048) {
                        int h = (n - 1024) >> 6;
                        newk[(((size_t)b * 16 + h) * 64 + d) * 1024 + s] = val;
                        Kt[(((size_t)b * 16 + h) * 2048 + 1024 + s) * 64 + d] = f2b(val);
                    } else {
                        int h = (n - 2048) >> 6;
                        newv[(((size_t)b * 16 + h) * 1024 + s) * 64 + d] = val;
                        Vt[(((size_t)b * 16 + h) * 64 + d) * 2048 + 1024 + s] = f2b(val);
                    }
                } else if (EPI == 1) {
                    size_t idx = (size_t)m * N + n;
                    outf[idx] = val + resid[idx];
                } else if (EPI == 2) {
                    float t = val + 0.044715f * val * val * val;
                    float gl = 0.5f * val * (1.0f + tanhf(0.7978845608028654f * t));
                    outb[(size_t)m * N + n] = f2b(gl);
                } else {
                    atomicAdd(outf + (size_t)m * N + n, val);
                }
            }
        }
    }
}

// ---------------- flash attention (unchanged from round 3) ----------------
__global__ __launch_bounds__(256) void attn_kernel(
    const u16* __restrict__ q, const u16* __restrict__ Kt,
    const u16* __restrict__ Vt, u16* __restrict__ aout)
{
    const int T = 2048;
    __shared__ u16 Ks[2][64][72];
    __shared__ u16 Vs[2][64][72];
    __shared__ u16 Ps[4][16][72];
    int tid = threadIdx.x;
    int wg = blockIdx.y * 16 + blockIdx.x;      // 0..511
    int xcd = wg & 7, local = wg >> 3;
    int bh = xcd * 4 + (local >> 4);            // 4 heads per XCD -> 2 MB KV L2-resident
    int s0 = (local & 15) * 64;
    int wave = tid >> 6, lane = tid & 63;
    int lrow = lane & 15, quad = lane >> 4;
    int sw = s0 + wave * 16;
    const u16* qb = q + (((size_t)bh * 1024) + sw + lrow) * 64;
    bf16x8 qf0 = *(const bf16x8*)(qb + quad * 8);
    bf16x8 qf1 = *(const bf16x8*)(qb + 32 + quad * 8);
    const u16* Kb = Kt + (size_t)bh * T * 64;
    const u16* Vb = Vt + (size_t)bh * 64 * T;
    int srow = tid >> 3, scol = (tid & 7) << 3;

    uint4 kr[2], vr[2];
#pragma unroll
    for (int i = 0; i < 2; i++) {
        kr[i] = *(const uint4*)(Kb + (size_t)(srow + i * 32) * 64 + scol);
        vr[i] = *(const uint4*)(Vb + (size_t)(srow + i * 32) * T + scol);
    }
#pragma unroll
    for (int i = 0; i < 2; i++) {
        *(uint4*)(&Ks[0][srow + i * 32][scol]) = kr[i];
        *(uint4*)(&Vs[0][srow + i * 32][scol]) = vr[i];
    }
#pragma unroll
    for (int i = 0; i < 2; i++) {
        kr[i] = *(const uint4*)(Kb + (size_t)(64 + srow + i * 32) * 64 + scol);
        vr[i] = *(const uint4*)(Vb + (size_t)(srow + i * 32) * T + 64 + scol);
    }
    __syncthreads();

    f32x4 Oacc[4] = {};
    float mrun = -1e30f, lrun = 0.0f;

    for (int t0 = 0; t0 < T; t0 += 64) {
        int cur = (t0 >> 6) & 1, nxt = cur ^ 1;
        if (t0 + 64 < T) {
#pragma unroll
            for (int i = 0; i < 2; i++) {
                *(uint4*)(&Ks[nxt][srow + i * 32][scol]) = kr[i];
                *(uint4*)(&Vs[nxt][srow + i * 32][scol]) = vr[i];
            }
        }
        if (t0 + 128 < T) {
#pragma unroll
            for (int i = 0; i < 2; i++) {
                kr[i] = *(const uint4*)(Kb + (size_t)(t0 + 128 + srow + i * 32) * 64 + scol);
                vr[i] = *(const uint4*)(Vb + (size_t)(srow + i * 32) * T + t0 + 128 + scol);
            }
        }
        f32x4 sc[4];
        __builtin_amdgcn_s_setprio(1);
#pragma unroll
        for (int tj = 0; tj < 4; tj++) {
            bf16x8 kf0 = *(const bf16x8*)(&Ks[cur][tj * 16 + lrow][quad * 8]);
            bf16x8 kf1 = *(const bf16x8*)(&Ks[cur][tj * 16 + lrow][32 + quad * 8]);
            f32x4 z = {};
            z = __builtin_amdgcn_mfma_f32_16x16x32_bf16(kf0, qf0, z, 0, 0, 0);
            z = __builtin_amdgcn_mfma_f32_16x16x32_bf16(kf1, qf1, z, 0, 0, 0);
            sc[tj] = z;
        }
        __builtin_amdgcn_s_setprio(0);
        float mx = sc[0][0];
#pragma unroll
        for (int tj = 0; tj < 4; tj++)
#pragma unroll
            for (int r = 0; r < 4; r++) mx = fmaxf(mx, sc[tj][r]);
        mx = fmaxf(mx, __shfl_xor(mx, 16));
        mx = fmaxf(mx, __shfl_xor(mx, 32));
        if (__any(mx > mrun + 8.0f)) {
            bool need = mx > mrun + 8.0f;
            float scl = need ? __expf(mrun - mx) : 1.0f;
            lrun *= scl;
            if (need) mrun = mx;
#pragma unroll
            for (int r = 0; r < 4; r++) {
                float sr = __shfl(scl, quad * 4 + r);
#pragma unroll
                for (int dj = 0; dj < 4; dj++) Oacc[dj][r] *= sr;
            }
        }
        float ps = 0.0f;
#pragma unroll
        for (int tj = 0; tj < 4; tj++) {
            float p0 = __expf(sc[tj][0] - mrun);
            float p1 = __expf(sc[tj][1] - mrun);
            float p2 = __expf(sc[tj][2] - mrun);
            float p3 = __expf(sc[tj][3] - mrun);
            ps += (p0 + p1) + (p2 + p3);
            ushort4 hh;
            hh.x = f2b(p0); hh.y = f2b(p1); hh.z = f2b(p2); hh.w = f2b(p3);
            *(ushort4*)(&Ps[wave][lrow][tj * 16 + quad * 4]) = hh;
        }
        ps += __shfl_xor(ps, 16);
        ps += __shfl_xor(ps, 32);
        lrun += ps;
        asm volatile("s_waitcnt lgkmcnt(0)" ::: "memory");
        __builtin_amdgcn_sched_barrier(0);
        __builtin_amdgcn_s_setprio(1);
#pragma unroll
        for (int ks = 0; ks < 2; ks++) {
            bf16x8 pf = *(const bf16x8*)(&Ps[wave][lrow][ks * 32 + quad * 8]);
#pragma unroll
            for (int dj = 0; dj < 4; dj++) {
                bf16x8 vf = *(const bf16x8*)(&Vs[cur][dj * 16 + lrow][ks * 32 + quad * 8]);
                Oacc[dj] = __builtin_amdgcn_mfma_f32_16x16x32_bf16(pf, vf, Oacc[dj], 0, 0, 0);
            }
        }
        __builtin_amdgcn_s_setprio(0);
        __syncthreads();
    }
    int b = bh >> 4, h = bh & 15;
#pragma unroll
    for (int r = 0; r < 4; r++) {
        float linv = 1.0f / __shfl(lrun, quad * 4 + r);
        int s = sw + quad * 4 + r;
#pragma unroll
        for (int dj = 0; dj < 4; dj++) {
            int d = dj * 16 + lrow;
            aout[((size_t)b * 1024 + s) * 1024 + h * 64 + d] = f2b(Oacc[dj][r] * linv);
        }
    }
}

extern "C" void kernel_launch(void* const* d_in, const int* in_sizes, int n_in,
                              void* d_out, int out_size, void* d_ws, size_t ws_size,
                              hipStream_t stream)
{
    const float* x      = (const float*)d_in[0];
    const float* kin    = (const float*)d_in[1];
    const float* vin    = (const float*)d_in[2];
    const float* ln1w   = (const float*)d_in[3];
    const float* ln1b   = (const float*)d_in[4];
    const float* ln2w   = (const float*)d_in[5];
    const float* ln2b   = (const float*)d_in[6];
    const float* w_attn = (const float*)d_in[7];
    const float* b_attn = (const float*)d_in[8];
    const float* w_proj = (const float*)d_in[9];
    const float* b_proj = (const float*)d_in[10];
    const float* w_fc   = (const float*)d_in[11];
    const float* b_fc   = (const float*)d_in[12];
    const float* w_fc2  = (const float*)d_in[13];
    const float* b_fc2  = (const float*)d_in[14];

    float* xout = (float*)d_out;
    float* newk = xout + 2097152;
    float* newv = newk + 2097152;

    char* w = (char*)d_ws;
    u16* wT_attn = (u16*)w;  w += 6291456;   // [3072,1024]
    u16* wT_proj = (u16*)w;  w += 2097152;   // [1024,1024]
    u16* wT_fc   = (u16*)w;  w += 8388608;   // [4096,1024]
    u16* wT_fc2  = (u16*)w;  w += 8388608;   // [1024,4096]
    u16* h1a     = (u16*)w;  w += 4194304;   // ln1 out, later attn out [B,S,D]
    u16* qh2     = (u16*)w;  w += 4194304;   // q [B,H,S,DH], later ln2 out
    u16* Kt      = (u16*)w;  w += 8388608;   // [B,H,2048,64]
    u16* Vt      = (u16*)w;  w += 8388608;   // [B,H,64,2048]
    u16* g       = (u16*)w;                  // [2048,4096] 16 MB

    dim3 blk(256);
    transpose_cvt<<<dim3(48, 16, 1), blk, 0, stream>>>(w_attn, wT_attn, 1024, 3072, 0, 1024);
    transpose_cvt<<<dim3(16, 16, 1), blk, 0, stream>>>(w_proj, wT_proj, 1024, 1024, 0, 1024);
    transpose_cvt<<<dim3(64, 16, 1), blk, 0, stream>>>(w_fc,   wT_fc,   1024, 4096, 0, 1024);
    transpose_cvt<<<dim3(16, 64, 1), blk, 0, stream>>>(w_fc2,  wT_fc2,  4096, 1024, 0, 4096);
    transpose_cvt<<<dim3(16, 1, 32), blk, 0, stream>>>(kin, Kt, 64, 1024, 131072, 64);
    transpose_cvt<<<dim3(1, 16, 32), blk, 0, stream>>>(vin, Vt, 1024, 64, 131072, 2048);

    ln_kernel<<<2048, blk, 0, stream>>>(x, ln1w, ln1b, h1a);

    gemm_bt<0><<<dim3(24, 16, 1), blk, 0, stream>>>(h1a, wT_attn, b_attn, 2048, 3072, 1024, 1024,
        nullptr, nullptr, nullptr, qh2, newk, newv, Kt, Vt);

    attn_kernel<<<dim3(16, 32), blk, 0, stream>>>(qh2, Kt, Vt, h1a);

    gemm_bt<1><<<dim3(8, 16, 1), blk, 0, stream>>>(h1a, wT_proj, b_proj, 2048, 1024, 1024, 1024,
        xout, x, nullptr, nullptr, nullptr, nullptr, nullptr, nullptr);

    ln_kernel<<<2048, blk, 0, stream>>>(xout, ln2w, ln2b, qh2);

    gemm_bt<2><<<dim3(32, 16, 1), blk, 0, stream>>>(qh2, wT_fc, b_fc, 2048, 4096, 1024, 1024,
        nullptr, nullptr, g, nullptr, nullptr, nullptr, nullptr, nullptr);

    // split-K x4: xout already holds post-attn residual; chunks atomicAdd partial+bias(chunk0)
    gemm_bt<3><<<dim3(8, 16, 4), blk, 0, stream>>>(g, wT_fc2, b_fc2, 2048, 1024, 4096, 1024,
        xout, nullptr, nullptr, nullptr, nullptr, nullptr, nullptr, nullptr);
}